// Round 13
// baseline (549.784 us; speedup 1.0000x reference)
//
#include <hip/hip_runtime.h>
#include <hip/hip_bf16.h>

// Problem constants (fixed by the reference)
#define NN 150000      // nodes
#define EE 600000      // edges
#define F_IN 32        // input node features
#define HD 128         // hidden dim
#define GG 2048        // graphs
#define CAP 28         // max degree bucket capacity (Poisson(4): P(deg>=28) ~ 4e-18)
#define NP 150016      // NN rounded up to 128-node blocks: 1172*128

typedef __attribute__((ext_vector_type(8))) short bf16x8;
typedef __attribute__((ext_vector_type(4))) float f32x4;

__device__ inline void split_bf16(float v, unsigned short& hi, unsigned short& lo) {
    __hip_bfloat16 h = __float2bfloat16(v);
    float hv = __bfloat162float(h);
    __hip_bfloat16 l = __float2bfloat16(v - hv);
    hi = *reinterpret_cast<unsigned short*>(&h);
    lo = *reinterpret_cast<unsigned short*>(&l);
}
__device__ inline unsigned short bf16_hi(float v) {
    __hip_bfloat16 h = __float2bfloat16(v);
    return *reinterpret_cast<unsigned short*>(&h);
}
__device__ inline unsigned short bf16_lo(float v) {
    __hip_bfloat16 h = __float2bfloat16(v);
    float hv = __bfloat162float(h);
    __hip_bfloat16 l = __float2bfloat16(v - hv);
    return *reinterpret_cast<unsigned short*>(&l);
}
__device__ inline float bf2f(unsigned short u) {
    union { unsigned int i; float f; } c;
    c.i = ((unsigned int)u) << 16;
    return c.f;
}

// ---------------------------------------------------------------------------
// Zero-init for workspace regions
// ---------------------------------------------------------------------------
__global__ void init_zero(int* __restrict__ cnt_node, int* __restrict__ cntg,
                          float* __restrict__ pooled) {
    int i = blockIdx.x * blockDim.x + threadIdx.x;
    if (i < NN) cnt_node[i] = 0;
    if (i < GG) cntg[i] = 0;
    if (i < GG * HD) pooled[i] = 0.f;
}

// ---------------------------------------------------------------------------
// CSR-bucket build + per-graph node counts (fused)
// ---------------------------------------------------------------------------
__global__ void build_graph(const int* __restrict__ ei, const int* __restrict__ batch,
                            int* __restrict__ cnt_node, int* __restrict__ cntg,
                            int* __restrict__ bucket) {
    int e = blockIdx.x * blockDim.x + threadIdx.x;
    if (e < NN) atomicAdd(&cntg[batch[e]], 1);
    if (e >= EE) return;
    int src = ei[e];         // edge_index[0]
    int dst = ei[EE + e];    // edge_index[1]
    int slot = atomicAdd(&cnt_node[dst], 1);
    if (slot < CAP) bucket[dst * CAP + slot] = src;
}

// ---------------------------------------------------------------------------
// Weight prep: fp32 W[K][H] -> split-bf16 packed in LANE-LINEAR fragment order
// ---------------------------------------------------------------------------
struct PrepDesc { const float* src; unsigned short* dhi; unsigned short* dlo; int K; };
struct PrepArgs { PrepDesc d[9]; };

__global__ void prep_weights(PrepArgs pa) {
    PrepDesc de = pa.d[blockIdx.y];
    int total = de.K * HD;
    int KS = de.K >> 5;
    for (int idx = blockIdx.x * blockDim.x + threadIdx.x; idx < total;
         idx += gridDim.x * blockDim.x) {
        int k = idx / HD, h = idx - (idx / HD) * HD;   // src is [K][H]
        unsigned short hi, lo;
        split_bf16(de.src[idx], hi, lo);
        int nt = h >> 4, m = h & 15;
        int ks = k >> 5, quad = (k >> 3) & 3, e = k & 7;
        int lane = quad * 16 + m;
        int pidx = ((nt * KS + ks) * 64 + lane) * 8 + e;
        de.dhi[pidx] = hi;
        de.dlo[pidx] = lo;
    }
}

// ---------------------------------------------------------------------------
// Fused GIN layer: gather-aggregate (fp32 accumulate) + 3-layer MLP on the
// matrix pipe, split-bf16 (hi+lo): D = Ah*Bh + Al*Bh + Ah*Bl (lo*lo dropped).
//
// BF16 activations (R12: halves lines/row). R13: the unrolled accumulate is
// TREE-REASSOCIATED — (r0+r1)+(r2+r3) — cutting the serial dependent chain
// on the running sum from 4-deep to 2-deep per element (rows/s was flat at
// ~4.3G across fp32-2row and bf16-4row: the chain, not line count, binds).
// launch_bounds(256,3), plain cached stores, POOL=true fuses mean-pool.
// ---------------------------------------------------------------------------
template <int K_IN, bool BF16IN, bool POOL>
__launch_bounds__(256, 3)
__global__ void gin_layer(const void* __restrict__ hin_,
                          const int* __restrict__ cnt_node,
                          const int* __restrict__ bucket,
                          const unsigned short* __restrict__ w1h, const unsigned short* __restrict__ w1l,
                          const float* __restrict__ b1,
                          const unsigned short* __restrict__ w2h, const unsigned short* __restrict__ w2l,
                          const float* __restrict__ b2,
                          const unsigned short* __restrict__ w3h, const unsigned short* __restrict__ w3l,
                          const float* __restrict__ b3,
                          unsigned short* __restrict__ out,   // bf16 activations (non-pool)
                          const int* __restrict__ batch,
                          float* __restrict__ pooled) {
    constexpr int KS1 = K_IN / 32;
    constexpr int UN = BF16IN ? 4 : (KS1 == 1 ? 8 : 2);   // gather unroll depth
    __shared__ unsigned short sh[4][32][HD + 8];   // 34816 B / block

    const int wave = threadIdx.x >> 6;
    const int lane = threadIdx.x & 63;
    const int m = lane & 15;      // node row within a 16-set / out-feature col
    const int quad = lane >> 4;   // 0..3
    const int nodeBase = blockIdx.x * 128 + wave * 32;

    const float* hf = (const float*)hin_;
    const unsigned short* hb = (const unsigned short*)hin_;

    // ---- fused aggregation: self + neighbors, fp32 -> split-bf16 A frags ----
    bf16x8 ah[2][KS1], al[2][KS1];
#pragma unroll
    for (int s = 0; s < 2; s++) {
        int node = nodeBase + s * 16 + m;
        node = node < NN ? node : NN - 1;
        float ag[KS1][8];
        if (BF16IN) {
            const unsigned short* rs = hb + (size_t)node * K_IN + quad * 8;
#pragma unroll
            for (int ks = 0; ks < KS1; ks++) {
                bf16x8 v = *(const bf16x8*)(rs + ks * 32);
#pragma unroll
                for (int e = 0; e < 8; e++) ag[ks][e] = bf2f((unsigned short)v[e]);
            }
        } else {
            const float* rs = hf + (size_t)node * K_IN + quad * 8;
#pragma unroll
            for (int ks = 0; ks < KS1; ks++) {
                float4 v0 = *(const float4*)(rs + ks * 32);
                float4 v1 = *(const float4*)(rs + ks * 32 + 4);
                ag[ks][0] = v0.x; ag[ks][1] = v0.y; ag[ks][2] = v0.z; ag[ks][3] = v0.w;
                ag[ks][4] = v1.x; ag[ks][5] = v1.y; ag[ks][6] = v1.z; ag[ks][7] = v1.w;
            }
        }
        int cnt = cnt_node[node];
        cnt = cnt < CAP ? cnt : CAP;
        const int* b = bucket + (size_t)node * CAP;
        int i = 0;
        if (BF16IN) {
            for (; i + UN <= cnt; i += UN) {
                bf16x8 v[UN][KS1];
#pragma unroll
                for (int j = 0; j < UN; j++) {
                    const unsigned short* r = hb + (size_t)b[i + j] * K_IN + quad * 8;
#pragma unroll
                    for (int ks = 0; ks < KS1; ks++)
                        v[j][ks] = *(const bf16x8*)(r + ks * 32);
                }
                // tree-reassociated: (r0+r1)+(r2+r3) -> ag chain depth 2, not 4
#pragma unroll
                for (int ks = 0; ks < KS1; ks++)
#pragma unroll
                    for (int e = 0; e < 8; e++) {
                        float t01 = bf2f((unsigned short)v[0][ks][e]) +
                                    bf2f((unsigned short)v[1][ks][e]);
                        float t23 = bf2f((unsigned short)v[2][ks][e]) +
                                    bf2f((unsigned short)v[3][ks][e]);
                        ag[ks][e] += t01 + t23;
                    }
            }
            for (; i < cnt; i++) {
                const unsigned short* r = hb + (size_t)b[i] * K_IN + quad * 8;
#pragma unroll
                for (int ks = 0; ks < KS1; ks++) {
                    bf16x8 v = *(const bf16x8*)(r + ks * 32);
#pragma unroll
                    for (int e = 0; e < 8; e++) ag[ks][e] += bf2f((unsigned short)v[e]);
                }
            }
        } else {
            for (; i + UN <= cnt; i += UN) {
                float4 v0[UN][KS1], v1[UN][KS1];
#pragma unroll
                for (int j = 0; j < UN; j++) {
                    const float* r = hf + (size_t)b[i + j] * K_IN + quad * 8;
#pragma unroll
                    for (int ks = 0; ks < KS1; ks++) {
                        v0[j][ks] = *(const float4*)(r + ks * 32);
                        v1[j][ks] = *(const float4*)(r + ks * 32 + 4);
                    }
                }
                // pairwise tree over the UN rows (depth log2(UN) + 1 on ag)
#pragma unroll
                for (int ks = 0; ks < KS1; ks++) {
                    float t0[8], t1[8];
#pragma unroll
                    for (int e = 0; e < 4; e++) {
                        float aA = (&v0[0][ks].x)[e], aB = (&v0[1][ks].x)[e];
                        float aC = (&v0[2][ks].x)[e], aD = (&v0[3][ks].x)[e];
                        float s01 = aA + aB, s23 = aC + aD;
                        if (UN == 8) {
                            float aE = (&v0[4][ks].x)[e], aF = (&v0[5][ks].x)[e];
                            float aG = (&v0[6][ks].x)[e], aH = (&v0[7][ks].x)[e];
                            s01 += aE + aF;
                            s23 += aG + aH;
                        }
                        t0[e] = s01 + s23;
                    }
#pragma unroll
                    for (int e = 0; e < 4; e++) {
                        float aA = (&v1[0][ks].x)[e], aB = (&v1[1][ks].x)[e];
                        float aC = (&v1[2][ks].x)[e], aD = (&v1[3][ks].x)[e];
                        float s01 = aA + aB, s23 = aC + aD;
                        if (UN == 8) {
                            float aE = (&v1[4][ks].x)[e], aF = (&v1[5][ks].x)[e];
                            float aG = (&v1[6][ks].x)[e], aH = (&v1[7][ks].x)[e];
                            s01 += aE + aF;
                            s23 += aG + aH;
                        }
                        t1[e] = s01 + s23;
                    }
#pragma unroll
                    for (int e = 0; e < 4; e++) {
                        ag[ks][e] += t0[e];
                        ag[ks][e + 4] += t1[e];
                    }
                }
            }
            for (; i < cnt; i++) {
                const float* r = hf + (size_t)b[i] * K_IN + quad * 8;
#pragma unroll
                for (int ks = 0; ks < KS1; ks++) {
                    float4 v0 = *(const float4*)(r + ks * 32);
                    float4 v1 = *(const float4*)(r + ks * 32 + 4);
                    ag[ks][0] += v0.x; ag[ks][1] += v0.y; ag[ks][2] += v0.z; ag[ks][3] += v0.w;
                    ag[ks][4] += v1.x; ag[ks][5] += v1.y; ag[ks][6] += v1.z; ag[ks][7] += v1.w;
                }
            }
        }
#pragma unroll
        for (int ks = 0; ks < KS1; ks++) {
            bf16x8 vh, vl;
#pragma unroll
            for (int e = 0; e < 8; e++) {
                unsigned short hi, lo;
                split_bf16(ag[ks][e], hi, lo);
                vh[e] = (short)hi;
                vl[e] = (short)lo;
            }
            ah[s][ks] = vh;
            al[s][ks] = vl;
        }
    }

    f32x4 acc[2][8];

    // ---- stage 1 ----
#pragma unroll
    for (int nt = 0; nt < 8; nt++) {
        bf16x8 bh[KS1], bl[KS1];
#pragma unroll
        for (int ks = 0; ks < KS1; ks++) {
            bh[ks] = *(const bf16x8*)(w1h + ((nt * KS1 + ks) * 64 + lane) * 8);
            bl[ks] = *(const bf16x8*)(w1l + ((nt * KS1 + ks) * 64 + lane) * 8);
        }
        f32x4 c0 = {0.f, 0.f, 0.f, 0.f};
        f32x4 c1 = {0.f, 0.f, 0.f, 0.f};
#pragma unroll
        for (int ks = 0; ks < KS1; ks++) {
            c0 = __builtin_amdgcn_mfma_f32_16x16x32_bf16(ah[0][ks], bh[ks], c0, 0, 0, 0);
            c1 = __builtin_amdgcn_mfma_f32_16x16x32_bf16(ah[1][ks], bh[ks], c1, 0, 0, 0);
            c0 = __builtin_amdgcn_mfma_f32_16x16x32_bf16(al[0][ks], bh[ks], c0, 0, 0, 0);
            c1 = __builtin_amdgcn_mfma_f32_16x16x32_bf16(al[1][ks], bh[ks], c1, 0, 0, 0);
            c0 = __builtin_amdgcn_mfma_f32_16x16x32_bf16(ah[0][ks], bl[ks], c0, 0, 0, 0);
            c1 = __builtin_amdgcn_mfma_f32_16x16x32_bf16(ah[1][ks], bl[ks], c1, 0, 0, 0);
        }
        acc[0][nt] = c0;
        acc[1][nt] = c1;
    }

    // ---- transpose 1->2 through single LDS buffer: hi pass then lo pass ----
    bf16x8 a2h[2][4], a2l[2][4];
#pragma unroll
    for (int s = 0; s < 2; s++)
#pragma unroll
        for (int nt = 0; nt < 8; nt++) {
            float bj = b1[nt * 16 + m];
#pragma unroll
            for (int r = 0; r < 4; r++)
                sh[wave][s * 16 + quad * 4 + r][nt * 16 + m] =
                    bf16_hi(fmaxf(acc[s][nt][r] + bj, 0.f));
        }
#pragma unroll
    for (int s = 0; s < 2; s++)
#pragma unroll
        for (int ks = 0; ks < 4; ks++)
            a2h[s][ks] = *(const bf16x8*)&sh[wave][s * 16 + m][ks * 32 + quad * 8];
#pragma unroll
    for (int s = 0; s < 2; s++)
#pragma unroll
        for (int nt = 0; nt < 8; nt++) {
            float bj = b1[nt * 16 + m];
#pragma unroll
            for (int r = 0; r < 4; r++)
                sh[wave][s * 16 + quad * 4 + r][nt * 16 + m] =
                    bf16_lo(fmaxf(acc[s][nt][r] + bj, 0.f));
        }
#pragma unroll
    for (int s = 0; s < 2; s++)
#pragma unroll
        for (int ks = 0; ks < 4; ks++)
            a2l[s][ks] = *(const bf16x8*)&sh[wave][s * 16 + m][ks * 32 + quad * 8];

    // ---- stage 2 ----
#pragma unroll
    for (int nt = 0; nt < 8; nt++) {
        bf16x8 bh[4], bl[4];
#pragma unroll
        for (int ks = 0; ks < 4; ks++) {
            bh[ks] = *(const bf16x8*)(w2h + ((nt * 4 + ks) * 64 + lane) * 8);
            bl[ks] = *(const bf16x8*)(w2l + ((nt * 4 + ks) * 64 + lane) * 8);
        }
        f32x4 c0 = {0.f, 0.f, 0.f, 0.f};
        f32x4 c1 = {0.f, 0.f, 0.f, 0.f};
#pragma unroll
        for (int ks = 0; ks < 4; ks++) {
            c0 = __builtin_amdgcn_mfma_f32_16x16x32_bf16(a2h[0][ks], bh[ks], c0, 0, 0, 0);
            c1 = __builtin_amdgcn_mfma_f32_16x16x32_bf16(a2h[1][ks], bh[ks], c1, 0, 0, 0);
            c0 = __builtin_amdgcn_mfma_f32_16x16x32_bf16(a2l[0][ks], bh[ks], c0, 0, 0, 0);
            c1 = __builtin_amdgcn_mfma_f32_16x16x32_bf16(a2l[1][ks], bh[ks], c1, 0, 0, 0);
            c0 = __builtin_amdgcn_mfma_f32_16x16x32_bf16(a2h[0][ks], bl[ks], c0, 0, 0, 0);
            c1 = __builtin_amdgcn_mfma_f32_16x16x32_bf16(a2h[1][ks], bl[ks], c1, 0, 0, 0);
        }
        acc[0][nt] = c0;
        acc[1][nt] = c1;
    }

    // ---- transpose 2->3 ----
#pragma unroll
    for (int s = 0; s < 2; s++)
#pragma unroll
        for (int nt = 0; nt < 8; nt++) {
            float bj = b2[nt * 16 + m];
#pragma unroll
            for (int r = 0; r < 4; r++)
                sh[wave][s * 16 + quad * 4 + r][nt * 16 + m] =
                    bf16_hi(fmaxf(acc[s][nt][r] + bj, 0.f));
        }
#pragma unroll
    for (int s = 0; s < 2; s++)
#pragma unroll
        for (int ks = 0; ks < 4; ks++)
            a2h[s][ks] = *(const bf16x8*)&sh[wave][s * 16 + m][ks * 32 + quad * 8];
#pragma unroll
    for (int s = 0; s < 2; s++)
#pragma unroll
        for (int nt = 0; nt < 8; nt++) {
            float bj = b2[nt * 16 + m];
#pragma unroll
            for (int r = 0; r < 4; r++)
                sh[wave][s * 16 + quad * 4 + r][nt * 16 + m] =
                    bf16_lo(fmaxf(acc[s][nt][r] + bj, 0.f));
        }
#pragma unroll
    for (int s = 0; s < 2; s++)
#pragma unroll
        for (int ks = 0; ks < 4; ks++)
            a2l[s][ks] = *(const bf16x8*)&sh[wave][s * 16 + m][ks * 32 + quad * 8];

    // ---- stage 3 ----
#pragma unroll
    for (int nt = 0; nt < 8; nt++) {
        bf16x8 bh[4], bl[4];
#pragma unroll
        for (int ks = 0; ks < 4; ks++) {
            bh[ks] = *(const bf16x8*)(w3h + ((nt * 4 + ks) * 64 + lane) * 8);
            bl[ks] = *(const bf16x8*)(w3l + ((nt * 4 + ks) * 64 + lane) * 8);
        }
        f32x4 c0 = {0.f, 0.f, 0.f, 0.f};
        f32x4 c1 = {0.f, 0.f, 0.f, 0.f};
#pragma unroll
        for (int ks = 0; ks < 4; ks++) {
            c0 = __builtin_amdgcn_mfma_f32_16x16x32_bf16(a2h[0][ks], bh[ks], c0, 0, 0, 0);
            c1 = __builtin_amdgcn_mfma_f32_16x16x32_bf16(a2h[1][ks], bh[ks], c1, 0, 0, 0);
            c0 = __builtin_amdgcn_mfma_f32_16x16x32_bf16(a2l[0][ks], bh[ks], c0, 0, 0, 0);
            c1 = __builtin_amdgcn_mfma_f32_16x16x32_bf16(a2l[1][ks], bh[ks], c1, 0, 0, 0);
            c0 = __builtin_amdgcn_mfma_f32_16x16x32_bf16(a2h[0][ks], bl[ks], c0, 0, 0, 0);
            c1 = __builtin_amdgcn_mfma_f32_16x16x32_bf16(a2h[1][ks], bl[ks], c1, 0, 0, 0);
        }
        acc[0][nt] = c0;
        acc[1][nt] = c1;
    }

    if (POOL) {
        // ---- fused mean-pool epilogue: per-wave LDS run-length reduce ----
        float* shf = (float*)&sh[wave][0][0];
#pragma unroll
        for (int h = 0; h < 2; h++) {
#pragma unroll
            for (int nt = 0; nt < 8; nt++) {
                float bj = b3[nt * 16 + m];
#pragma unroll
                for (int r = 0; r < 4; r++)
                    shf[(quad * 4 + r) * 132 + nt * 16 + m] =
                        fmaxf(acc[h][nt][r] + bj, 0.f);
            }
            int c0 = lane * 2;
            float run0 = 0.f, run1 = 0.f;
            int gp = -1;
            for (int rrow = 0; rrow < 16; rrow++) {
                int node = nodeBase + h * 16 + rrow;
                if (node >= NN) break;
                int g = batch[node];
                float2 xv = *(const float2*)&shf[rrow * 132 + c0];
                if (g != gp) {
                    if (gp >= 0) {
                        atomicAdd(&pooled[(size_t)gp * HD + c0 + 0], run0);
                        atomicAdd(&pooled[(size_t)gp * HD + c0 + 1], run1);
                    }
                    run0 = xv.x; run1 = xv.y; gp = g;
                } else {
                    run0 += xv.x; run1 += xv.y;
                }
            }
            if (gp >= 0) {
                atomicAdd(&pooled[(size_t)gp * HD + c0 + 0], run0);
                atomicAdd(&pooled[(size_t)gp * HD + c0 + 1], run1);
            }
        }
    } else {
        // ---- epilogue: bf16 restage through LDS, coalesced row stores ----
#pragma unroll
        for (int s = 0; s < 2; s++)
#pragma unroll
            for (int nt = 0; nt < 8; nt++) {
                float bj = b3[nt * 16 + m];
#pragma unroll
                for (int r = 0; r < 4; r++)
                    sh[wave][s * 16 + quad * 4 + r][nt * 16 + m] =
                        bf16_hi(fmaxf(acc[s][nt][r] + bj, 0.f));
            }
#pragma unroll
        for (int io = 0; io < 8; io++) {
            int row32 = io * 4 + quad;
            int col = m * 8;
            int n2 = nodeBase + row32;
            bf16x8 v = *(const bf16x8*)&sh[wave][row32][col];
            if (n2 < NN) *(bf16x8*)&out[(size_t)n2 * HD + col] = v;
        }
    }
}

// ---------------------------------------------------------------------------
// Classifier head: one block (128 threads) per graph.
// ---------------------------------------------------------------------------
__launch_bounds__(128)
__global__ void head(const float* __restrict__ pooled, const int* __restrict__ cntg,
                     const float* __restrict__ fc0_w, const float* __restrict__ fc0_b,
                     const float* __restrict__ fc1_w, const float* __restrict__ fc1_b,
                     const float* __restrict__ out_w, const float* __restrict__ out_b,
                     float* __restrict__ out) {
    int g = blockIdx.x;
    int j = threadIdx.x;
    __shared__ float s0[HD];
    __shared__ float s1[HD];
    int c = cntg[g];
    float cf = (float)(c > 1 ? c : 1);
    s0[j] = pooled[(size_t)g * HD + j] / cf;
    __syncthreads();

    float acc = fc0_b[j];
    for (int k = 0; k < HD; k += 4) {
        float4 hv = *(const float4*)&s0[k];
        acc = fmaf(hv.x, fc0_w[(k + 0) * HD + j], acc);
        acc = fmaf(hv.y, fc0_w[(k + 1) * HD + j], acc);
        acc = fmaf(hv.z, fc0_w[(k + 2) * HD + j], acc);
        acc = fmaf(hv.w, fc0_w[(k + 3) * HD + j], acc);
    }
    s1[j] = fmaxf(acc, 0.0f);
    __syncthreads();

    acc = fc1_b[j];
    for (int k = 0; k < HD; k += 4) {
        float4 hv = *(const float4*)&s1[k];
        acc = fmaf(hv.x, fc1_w[(k + 0) * HD + j], acc);
        acc = fmaf(hv.y, fc1_w[(k + 1) * HD + j], acc);
        acc = fmaf(hv.z, fc1_w[(k + 2) * HD + j], acc);
        acc = fmaf(hv.w, fc1_w[(k + 3) * HD + j], acc);
    }
    float v = fmaxf(acc, 0.0f);

    float p0 = v * out_w[j * 2 + 0];
    float p1 = v * out_w[j * 2 + 1];
    __syncthreads();
    s0[j] = p0;
    s1[j] = p1;
    __syncthreads();
    for (int off = 64; off >= 1; off >>= 1) {
        if (j < off) {
            s0[j] += s0[j + off];
            s1[j] += s1[j + off];
        }
        __syncthreads();
    }
    if (j == 0) {
        out[(size_t)g * 2 + 0] = s0[0] + out_b[0];
        out[(size_t)g * 2 + 1] = s1[0] + out_b[1];
    }
}

// ---------------------------------------------------------------------------
extern "C" void kernel_launch(void* const* d_in, const int* in_sizes, int n_in,
                              void* d_out, int out_size, void* d_ws, size_t ws_size,
                              hipStream_t stream) {
    const float* x     = (const float*)d_in[0];
    const int*   ei    = (const int*)d_in[1];
    const int*   batch = (const int*)d_in[2];
    const float* cw[3][6];
    for (int i = 0; i < 3; i++)
        for (int k = 0; k < 6; k++) cw[i][k] = (const float*)d_in[3 + 6 * i + k];
    const float* fc0_w = (const float*)d_in[21];
    const float* fc0_b = (const float*)d_in[22];
    const float* fc1_w = (const float*)d_in[23];
    const float* fc1_b = (const float*)d_in[24];
    const float* out_w = (const float*)d_in[25];
    const float* out_b = (const float*)d_in[26];
    float* out = (float*)d_out;

    char* ws = (char*)d_ws;
    size_t off = 0;
    auto carve = [&](size_t bytes) {
        void* p = ws + off;
        off += (bytes + 255) & ~(size_t)255;
        return p;
    };
    int*   cnt_node = (int*)carve((size_t)NN * 4);
    int*   cntg     = (int*)carve((size_t)GG * 4);
    float* pooled   = (float*)carve((size_t)GG * HD * 4);
    int*   bucket   = (int*)carve((size_t)NN * CAP * 4);
    unsigned short* hA = (unsigned short*)carve((size_t)NP * HD * 2);
    unsigned short* hB = (unsigned short*)carve((size_t)NP * HD * 2);
    unsigned short* wHi[9];
    unsigned short* wLo[9];
    int wK[9] = {F_IN, HD, HD, HD, HD, HD, HD, HD, HD};
    for (int i = 0; i < 9; i++) {
        wHi[i] = (unsigned short*)carve((size_t)wK[i] * HD * 2);
        wLo[i] = (unsigned short*)carve((size_t)wK[i] * HD * 2);
    }
    (void)ws_size;

    init_zero<<<(GG * HD + 255) / 256, 256, 0, stream>>>(cnt_node, cntg, pooled);
    build_graph<<<(EE + 255) / 256, 256, 0, stream>>>(ei, batch, cnt_node, cntg, bucket);

    PrepArgs pa;
    for (int l = 0; l < 3; l++)
        for (int s = 0; s < 3; s++) {
            int i = l * 3 + s;
            pa.d[i].src = cw[l][2 * s];
            pa.d[i].dhi = wHi[i];
            pa.d[i].dlo = wLo[i];
            pa.d[i].K = wK[i];
        }
    prep_weights<<<dim3(16, 9), 256, 0, stream>>>(pa);

    const int blocks = NP / 128;  // 1172

    // ---- GIN layer 0 (K=32, fp32 in): x -> hA (bf16) ----
    gin_layer<F_IN, false, false><<<blocks, 256, 0, stream>>>(x, cnt_node, bucket,
        wHi[0], wLo[0], cw[0][1], wHi[1], wLo[1], cw[0][3], wHi[2], wLo[2], cw[0][5],
        hA, batch, pooled);
    // ---- GIN layer 1 (bf16 in): hA -> hB (bf16) ----
    gin_layer<HD, true, false><<<blocks, 256, 0, stream>>>(hA, cnt_node, bucket,
        wHi[3], wLo[3], cw[1][1], wHi[4], wLo[4], cw[1][3], wHi[5], wLo[5], cw[1][5],
        hB, batch, pooled);
    // ---- GIN layer 2 (bf16 in): hB -> pooled (fused mean-pool sum) ----
    gin_layer<HD, true, true><<<blocks, 256, 0, stream>>>(hB, cnt_node, bucket,
        wHi[6], wLo[6], cw[2][1], wHi[7], wLo[7], cw[2][3], wHi[8], wLo[8], cw[2][5],
        nullptr, batch, pooled);

    // ---- head ----
    head<<<GG, 128, 0, stream>>>(pooled, cntg, fc0_w, fc0_b, fc1_w, fc1_b, out_w, out_b, out);
}

// Round 14
// 548.269 us; speedup vs baseline: 1.0028x; 1.0028x over previous
//
#include <hip/hip_runtime.h>
#include <hip/hip_bf16.h>

// Problem constants (fixed by the reference)
#define NN 150000      // nodes
#define EE 600000      // edges
#define F_IN 32        // input node features
#define HD 128         // hidden dim
#define GG 2048        // graphs
#define CAP 32         // max degree bucket capacity; 32 -> 128B-aligned index rows
#define NP 150016      // NN rounded up to 128-node blocks: 1172*128

typedef __attribute__((ext_vector_type(8))) short bf16x8;
typedef __attribute__((ext_vector_type(4))) float f32x4;

__device__ inline void split_bf16(float v, unsigned short& hi, unsigned short& lo) {
    __hip_bfloat16 h = __float2bfloat16(v);
    float hv = __bfloat162float(h);
    __hip_bfloat16 l = __float2bfloat16(v - hv);
    hi = *reinterpret_cast<unsigned short*>(&h);
    lo = *reinterpret_cast<unsigned short*>(&l);
}
__device__ inline unsigned short bf16_hi(float v) {
    __hip_bfloat16 h = __float2bfloat16(v);
    return *reinterpret_cast<unsigned short*>(&h);
}
__device__ inline unsigned short bf16_lo(float v) {
    __hip_bfloat16 h = __float2bfloat16(v);
    float hv = __bfloat162float(h);
    __hip_bfloat16 l = __float2bfloat16(v - hv);
    return *reinterpret_cast<unsigned short*>(&l);
}
__device__ inline float bf2f(unsigned short u) {
    union { unsigned int i; float f; } c;
    c.i = ((unsigned int)u) << 16;
    return c.f;
}

// ---------------------------------------------------------------------------
// Zero-init for workspace regions
// ---------------------------------------------------------------------------
__global__ void init_zero(int* __restrict__ cnt_node, int* __restrict__ cntg,
                          float* __restrict__ pooled) {
    int i = blockIdx.x * blockDim.x + threadIdx.x;
    if (i < NN) cnt_node[i] = 0;
    if (i < GG) cntg[i] = 0;
    if (i < GG * HD) pooled[i] = 0.f;
}

// ---------------------------------------------------------------------------
// CSR-bucket build + per-graph node counts (fused)
// ---------------------------------------------------------------------------
__global__ void build_graph(const int* __restrict__ ei, const int* __restrict__ batch,
                            int* __restrict__ cnt_node, int* __restrict__ cntg,
                            int* __restrict__ bucket) {
    int e = blockIdx.x * blockDim.x + threadIdx.x;
    if (e < NN) atomicAdd(&cntg[batch[e]], 1);
    if (e >= EE) return;
    int src = ei[e];         // edge_index[0]
    int dst = ei[EE + e];    // edge_index[1]
    int slot = atomicAdd(&cnt_node[dst], 1);
    if (slot < CAP) bucket[dst * CAP + slot] = src;
}

// ---------------------------------------------------------------------------
// Weight prep: fp32 W[K][H] -> split-bf16 packed in LANE-LINEAR fragment order
// ---------------------------------------------------------------------------
struct PrepDesc { const float* src; unsigned short* dhi; unsigned short* dlo; int K; };
struct PrepArgs { PrepDesc d[9]; };

__global__ void prep_weights(PrepArgs pa) {
    PrepDesc de = pa.d[blockIdx.y];
    int total = de.K * HD;
    int KS = de.K >> 5;
    for (int idx = blockIdx.x * blockDim.x + threadIdx.x; idx < total;
         idx += gridDim.x * blockDim.x) {
        int k = idx / HD, h = idx - (idx / HD) * HD;   // src is [K][H]
        unsigned short hi, lo;
        split_bf16(de.src[idx], hi, lo);
        int nt = h >> 4, m = h & 15;
        int ks = k >> 5, quad = (k >> 3) & 3, e = k & 7;
        int lane = quad * 16 + m;
        int pidx = ((nt * KS + ks) * 64 + lane) * 8 + e;
        de.dhi[pidx] = hi;
        de.dlo[pidx] = lo;
    }
}

// ---------------------------------------------------------------------------
// Fused GIN layer: gather-aggregate (fp32 accumulate) + 3-layer MLP on the
// matrix pipe, split-bf16 (hi+lo): D = Ah*Bh + Al*Bh + Ah*Bl (lo*lo dropped).
//
// R14 experiment: COOP gather (layer 1 only) fetches each neighbor row as ONE
// contiguous 256B request (16 lanes x 16B, 4 rows/instr) restaged through the
// per-wave LDS buffer, vs the baseline scattered 64B-segment gather (layer 2,
// same loads, pool epilogue) — a direct within-bench A/B on request
// granularity, the one dimension not yet probed (rows/s has been invariant at
// ~5G across row size / unroll / registers / occupancy / chain depth).
// ---------------------------------------------------------------------------
template <int K_IN, bool BF16IN, bool COOP, bool POOL>
__launch_bounds__(256, 3)
__global__ void gin_layer(const void* __restrict__ hin_,
                          const int* __restrict__ cnt_node,
                          const int* __restrict__ bucket,
                          const unsigned short* __restrict__ w1h, const unsigned short* __restrict__ w1l,
                          const float* __restrict__ b1,
                          const unsigned short* __restrict__ w2h, const unsigned short* __restrict__ w2l,
                          const float* __restrict__ b2,
                          const unsigned short* __restrict__ w3h, const unsigned short* __restrict__ w3l,
                          const float* __restrict__ b3,
                          unsigned short* __restrict__ out,   // bf16 activations (non-pool)
                          const int* __restrict__ batch,
                          float* __restrict__ pooled) {
    constexpr int KS1 = K_IN / 32;
    constexpr int UN = BF16IN ? 4 : (KS1 == 1 ? 8 : 2);   // gather unroll depth
    __shared__ unsigned short sh[4][32][HD + 8];   // 34816 B
    __shared__ int shIdx[4][16][CAP];              // 8192 B (coop index staging)

    const int wave = threadIdx.x >> 6;
    const int lane = threadIdx.x & 63;
    const int m = lane & 15;      // node row within a 16-set / out-feature col
    const int quad = lane >> 4;   // 0..3
    const int nodeBase = blockIdx.x * 128 + wave * 32;

    const float* hf = (const float*)hin_;
    const unsigned short* hb = (const unsigned short*)hin_;

    // ---- fused aggregation: self + neighbors, fp32 -> split-bf16 A frags ----
    bf16x8 ah[2][KS1], al[2][KS1];
#pragma unroll
    for (int s = 0; s < 2; s++) {
        int node = nodeBase + s * 16 + m;
        node = node < NN ? node : NN - 1;
        float ag[KS1][8];
        if (BF16IN) {
            const unsigned short* rs = hb + (size_t)node * K_IN + quad * 8;
#pragma unroll
            for (int ks = 0; ks < KS1; ks++) {
                bf16x8 v = *(const bf16x8*)(rs + ks * 32);
#pragma unroll
                for (int e = 0; e < 8; e++) ag[ks][e] = bf2f((unsigned short)v[e]);
            }
        } else {
            const float* rs = hf + (size_t)node * K_IN + quad * 8;
#pragma unroll
            for (int ks = 0; ks < KS1; ks++) {
                float4 v0 = *(const float4*)(rs + ks * 32);
                float4 v1 = *(const float4*)(rs + ks * 32 + 4);
                ag[ks][0] = v0.x; ag[ks][1] = v0.y; ag[ks][2] = v0.z; ag[ks][3] = v0.w;
                ag[ks][4] = v1.x; ag[ks][5] = v1.y; ag[ks][6] = v1.z; ag[ks][7] = v1.w;
            }
        }
        int cnt = cnt_node[node];
        cnt = cnt < CAP ? cnt : CAP;

        if constexpr (COOP && BF16IN) {
            // ---- cooperative 256B-row gather through LDS ----
            // Stage the 16 nodes' index rows (2KB contiguous) into LDS.
            {
                const int* bsrc = bucket + (size_t)(nodeBase + s * 16) * CAP;
#pragma unroll
                for (int it = 0; it < 8; it++) {
                    int fi = it * 64 + lane;            // 0..511
                    int id = bsrc[fi];
                    id = ((unsigned)id < (unsigned)NN) ? id : 0;  // clamp unwritten slots
                    shIdx[wave][fi >> 5][fi & 31] = id;
                }
            }
            // wave max of cnt over the 16 nodes of this s-half
            int kmax = cnt;
#pragma unroll
            for (int off = 1; off < 64; off <<= 1) {
                int o = __shfl_xor(kmax, off);
                kmax = kmax > o ? kmax : o;
            }
            const int rl = lane >> 4;           // row-in-instr 0..3
            const int ch = (lane & 15) * 8;     // 16B chunk offset (shorts)
            bf16x8 vA[4], vB[4];
            if (kmax > 0) {
#pragma unroll
                for (int j = 0; j < 4; j++) {
                    int nb = shIdx[wave][4 * j + rl][0];
                    vA[j] = *(const bf16x8*)(hb + (size_t)nb * K_IN + ch);
                }
            }
            for (int k = 0; k < kmax; k++) {
                bf16x8* vc = (k & 1) ? vB : vA;
                bf16x8* vn = (k & 1) ? vA : vB;
                if (k + 1 < kmax) {
#pragma unroll
                    for (int j = 0; j < 4; j++) {
                        int nb = shIdx[wave][4 * j + rl][k + 1];
                        vn[j] = *(const bf16x8*)(hb + (size_t)nb * K_IN + ch);
                    }
                }
                // restage this k-level's 16 rows (wave-synchronous LDS)
#pragma unroll
                for (int j = 0; j < 4; j++)
                    *(bf16x8*)&sh[wave][4 * j + rl][ch] = vc[j];
                // read back own node's row in fragment layout, accumulate
                if (k < cnt) {
#pragma unroll
                    for (int ks = 0; ks < KS1; ks++) {
                        bf16x8 v = *(const bf16x8*)&sh[wave][m][ks * 32 + quad * 8];
#pragma unroll
                        for (int e = 0; e < 8; e++)
                            ag[ks][e] += bf2f((unsigned short)v[e]);
                    }
                }
            }
        } else if (BF16IN) {
            const int* b = bucket + (size_t)node * CAP;
            int i = 0;
            for (; i + UN <= cnt; i += UN) {
                bf16x8 v[UN][KS1];
#pragma unroll
                for (int j = 0; j < UN; j++) {
                    const unsigned short* r = hb + (size_t)b[i + j] * K_IN + quad * 8;
#pragma unroll
                    for (int ks = 0; ks < KS1; ks++)
                        v[j][ks] = *(const bf16x8*)(r + ks * 32);
                }
#pragma unroll
                for (int ks = 0; ks < KS1; ks++)
#pragma unroll
                    for (int e = 0; e < 8; e++) {
                        float t01 = bf2f((unsigned short)v[0][ks][e]) +
                                    bf2f((unsigned short)v[1][ks][e]);
                        float t23 = bf2f((unsigned short)v[2][ks][e]) +
                                    bf2f((unsigned short)v[3][ks][e]);
                        ag[ks][e] += t01 + t23;
                    }
            }
            for (; i < cnt; i++) {
                const unsigned short* r = hb + (size_t)b[i] * K_IN + quad * 8;
#pragma unroll
                for (int ks = 0; ks < KS1; ks++) {
                    bf16x8 v = *(const bf16x8*)(r + ks * 32);
#pragma unroll
                    for (int e = 0; e < 8; e++) ag[ks][e] += bf2f((unsigned short)v[e]);
                }
            }
        } else {
            const int* b = bucket + (size_t)node * CAP;
            int i = 0;
            for (; i + UN <= cnt; i += UN) {
                float4 v0[UN][KS1], v1[UN][KS1];
#pragma unroll
                for (int j = 0; j < UN; j++) {
                    const float* r = hf + (size_t)b[i + j] * K_IN + quad * 8;
#pragma unroll
                    for (int ks = 0; ks < KS1; ks++) {
                        v0[j][ks] = *(const float4*)(r + ks * 32);
                        v1[j][ks] = *(const float4*)(r + ks * 32 + 4);
                    }
                }
#pragma unroll
                for (int ks = 0; ks < KS1; ks++) {
#pragma unroll
                    for (int e = 0; e < 4; e++) {
                        float s01 = (&v0[0][ks].x)[e] + (&v0[1][ks].x)[e];
                        float s23 = (&v0[2][ks].x)[e] + (&v0[3][ks].x)[e];
                        if (UN == 8) {
                            s01 += (&v0[4][ks].x)[e] + (&v0[5][ks].x)[e];
                            s23 += (&v0[6][ks].x)[e] + (&v0[7][ks].x)[e];
                        }
                        ag[ks][e] += s01 + s23;
                    }
#pragma unroll
                    for (int e = 0; e < 4; e++) {
                        float s01 = (&v1[0][ks].x)[e] + (&v1[1][ks].x)[e];
                        float s23 = (&v1[2][ks].x)[e] + (&v1[3][ks].x)[e];
                        if (UN == 8) {
                            s01 += (&v1[4][ks].x)[e] + (&v1[5][ks].x)[e];
                            s23 += (&v1[6][ks].x)[e] + (&v1[7][ks].x)[e];
                        }
                        ag[ks][e + 4] += s01 + s23;
                    }
                }
            }
            for (; i < cnt; i++) {
                const float* r = hf + (size_t)b[i] * K_IN + quad * 8;
#pragma unroll
                for (int ks = 0; ks < KS1; ks++) {
                    float4 v0 = *(const float4*)(r + ks * 32);
                    float4 v1 = *(const float4*)(r + ks * 32 + 4);
                    ag[ks][0] += v0.x; ag[ks][1] += v0.y; ag[ks][2] += v0.z; ag[ks][3] += v0.w;
                    ag[ks][4] += v1.x; ag[ks][5] += v1.y; ag[ks][6] += v1.z; ag[ks][7] += v1.w;
                }
            }
        }
#pragma unroll
        for (int ks = 0; ks < KS1; ks++) {
            bf16x8 vh, vl;
#pragma unroll
            for (int e = 0; e < 8; e++) {
                unsigned short hi, lo;
                split_bf16(ag[ks][e], hi, lo);
                vh[e] = (short)hi;
                vl[e] = (short)lo;
            }
            ah[s][ks] = vh;
            al[s][ks] = vl;
        }
    }

    f32x4 acc[2][8];

    // ---- stage 1 ----
#pragma unroll
    for (int nt = 0; nt < 8; nt++) {
        bf16x8 bh[KS1], bl[KS1];
#pragma unroll
        for (int ks = 0; ks < KS1; ks++) {
            bh[ks] = *(const bf16x8*)(w1h + ((nt * KS1 + ks) * 64 + lane) * 8);
            bl[ks] = *(const bf16x8*)(w1l + ((nt * KS1 + ks) * 64 + lane) * 8);
        }
        f32x4 c0 = {0.f, 0.f, 0.f, 0.f};
        f32x4 c1 = {0.f, 0.f, 0.f, 0.f};
#pragma unroll
        for (int ks = 0; ks < KS1; ks++) {
            c0 = __builtin_amdgcn_mfma_f32_16x16x32_bf16(ah[0][ks], bh[ks], c0, 0, 0, 0);
            c1 = __builtin_amdgcn_mfma_f32_16x16x32_bf16(ah[1][ks], bh[ks], c1, 0, 0, 0);
            c0 = __builtin_amdgcn_mfma_f32_16x16x32_bf16(al[0][ks], bh[ks], c0, 0, 0, 0);
            c1 = __builtin_amdgcn_mfma_f32_16x16x32_bf16(al[1][ks], bh[ks], c1, 0, 0, 0);
            c0 = __builtin_amdgcn_mfma_f32_16x16x32_bf16(ah[0][ks], bl[ks], c0, 0, 0, 0);
            c1 = __builtin_amdgcn_mfma_f32_16x16x32_bf16(ah[1][ks], bl[ks], c1, 0, 0, 0);
        }
        acc[0][nt] = c0;
        acc[1][nt] = c1;
    }

    // ---- transpose 1->2 through single LDS buffer: hi pass then lo pass ----
    bf16x8 a2h[2][4], a2l[2][4];
#pragma unroll
    for (int s = 0; s < 2; s++)
#pragma unroll
        for (int nt = 0; nt < 8; nt++) {
            float bj = b1[nt * 16 + m];
#pragma unroll
            for (int r = 0; r < 4; r++)
                sh[wave][s * 16 + quad * 4 + r][nt * 16 + m] =
                    bf16_hi(fmaxf(acc[s][nt][r] + bj, 0.f));
        }
#pragma unroll
    for (int s = 0; s < 2; s++)
#pragma unroll
        for (int ks = 0; ks < 4; ks++)
            a2h[s][ks] = *(const bf16x8*)&sh[wave][s * 16 + m][ks * 32 + quad * 8];
#pragma unroll
    for (int s = 0; s < 2; s++)
#pragma unroll
        for (int nt = 0; nt < 8; nt++) {
            float bj = b1[nt * 16 + m];
#pragma unroll
            for (int r = 0; r < 4; r++)
                sh[wave][s * 16 + quad * 4 + r][nt * 16 + m] =
                    bf16_lo(fmaxf(acc[s][nt][r] + bj, 0.f));
        }
#pragma unroll
    for (int s = 0; s < 2; s++)
#pragma unroll
        for (int ks = 0; ks < 4; ks++)
            a2l[s][ks] = *(const bf16x8*)&sh[wave][s * 16 + m][ks * 32 + quad * 8];

    // ---- stage 2 ----
#pragma unroll
    for (int nt = 0; nt < 8; nt++) {
        bf16x8 bh[4], bl[4];
#pragma unroll
        for (int ks = 0; ks < 4; ks++) {
            bh[ks] = *(const bf16x8*)(w2h + ((nt * 4 + ks) * 64 + lane) * 8);
            bl[ks] = *(const bf16x8*)(w2l + ((nt * 4 + ks) * 64 + lane) * 8);
        }
        f32x4 c0 = {0.f, 0.f, 0.f, 0.f};
        f32x4 c1 = {0.f, 0.f, 0.f, 0.f};
#pragma unroll
        for (int ks = 0; ks < 4; ks++) {
            c0 = __builtin_amdgcn_mfma_f32_16x16x32_bf16(a2h[0][ks], bh[ks], c0, 0, 0, 0);
            c1 = __builtin_amdgcn_mfma_f32_16x16x32_bf16(a2h[1][ks], bh[ks], c1, 0, 0, 0);
            c0 = __builtin_amdgcn_mfma_f32_16x16x32_bf16(a2l[0][ks], bh[ks], c0, 0, 0, 0);
            c1 = __builtin_amdgcn_mfma_f32_16x16x32_bf16(a2l[1][ks], bh[ks], c1, 0, 0, 0);
            c0 = __builtin_amdgcn_mfma_f32_16x16x32_bf16(a2h[0][ks], bl[ks], c0, 0, 0, 0);
            c1 = __builtin_amdgcn_mfma_f32_16x16x32_bf16(a2h[1][ks], bl[ks], c1, 0, 0, 0);
        }
        acc[0][nt] = c0;
        acc[1][nt] = c1;
    }

    // ---- transpose 2->3 ----
#pragma unroll
    for (int s = 0; s < 2; s++)
#pragma unroll
        for (int nt = 0; nt < 8; nt++) {
            float bj = b2[nt * 16 + m];
#pragma unroll
            for (int r = 0; r < 4; r++)
                sh[wave][s * 16 + quad * 4 + r][nt * 16 + m] =
                    bf16_hi(fmaxf(acc[s][nt][r] + bj, 0.f));
        }
#pragma unroll
    for (int s = 0; s < 2; s++)
#pragma unroll
        for (int ks = 0; ks < 4; ks++)
            a2h[s][ks] = *(const bf16x8*)&sh[wave][s * 16 + m][ks * 32 + quad * 8];
#pragma unroll
    for (int s = 0; s < 2; s++)
#pragma unroll
        for (int nt = 0; nt < 8; nt++) {
            float bj = b2[nt * 16 + m];
#pragma unroll
            for (int r = 0; r < 4; r++)
                sh[wave][s * 16 + quad * 4 + r][nt * 16 + m] =
                    bf16_lo(fmaxf(acc[s][nt][r] + bj, 0.f));
        }
#pragma unroll
    for (int s = 0; s < 2; s++)
#pragma unroll
        for (int ks = 0; ks < 4; ks++)
            a2l[s][ks] = *(const bf16x8*)&sh[wave][s * 16 + m][ks * 32 + quad * 8];

    // ---- stage 3 ----
#pragma unroll
    for (int nt = 0; nt < 8; nt++) {
        bf16x8 bh[4], bl[4];
#pragma unroll
        for (int ks = 0; ks < 4; ks++) {
            bh[ks] = *(const bf16x8*)(w3h + ((nt * 4 + ks) * 64 + lane) * 8);
            bl[ks] = *(const bf16x8*)(w3l + ((nt * 4 + ks) * 64 + lane) * 8);
        }
        f32x4 c0 = {0.f, 0.f, 0.f, 0.f};
        f32x4 c1 = {0.f, 0.f, 0.f, 0.f};
#pragma unroll
        for (int ks = 0; ks < 4; ks++) {
            c0 = __builtin_amdgcn_mfma_f32_16x16x32_bf16(a2h[0][ks], bh[ks], c0, 0, 0, 0);
            c1 = __builtin_amdgcn_mfma_f32_16x16x32_bf16(a2h[1][ks], bh[ks], c1, 0, 0, 0);
            c0 = __builtin_amdgcn_mfma_f32_16x16x32_bf16(a2l[0][ks], bh[ks], c0, 0, 0, 0);
            c1 = __builtin_amdgcn_mfma_f32_16x16x32_bf16(a2l[1][ks], bh[ks], c1, 0, 0, 0);
            c0 = __builtin_amdgcn_mfma_f32_16x16x32_bf16(a2h[0][ks], bl[ks], c0, 0, 0, 0);
            c1 = __builtin_amdgcn_mfma_f32_16x16x32_bf16(a2h[1][ks], bl[ks], c1, 0, 0, 0);
        }
        acc[0][nt] = c0;
        acc[1][nt] = c1;
    }

    if (POOL) {
        // ---- fused mean-pool epilogue: per-wave LDS run-length reduce ----
        float* shf = (float*)&sh[wave][0][0];
#pragma unroll
        for (int h = 0; h < 2; h++) {
#pragma unroll
            for (int nt = 0; nt < 8; nt++) {
                float bj = b3[nt * 16 + m];
#pragma unroll
                for (int r = 0; r < 4; r++)
                    shf[(quad * 4 + r) * 132 + nt * 16 + m] =
                        fmaxf(acc[h][nt][r] + bj, 0.f);
            }
            int c0 = lane * 2;
            float run0 = 0.f, run1 = 0.f;
            int gp = -1;
            for (int rrow = 0; rrow < 16; rrow++) {
                int node = nodeBase + h * 16 + rrow;
                if (node >= NN) break;
                int g = batch[node];
                float2 xv = *(const float2*)&shf[rrow * 132 + c0];
                if (g != gp) {
                    if (gp >= 0) {
                        atomicAdd(&pooled[(size_t)gp * HD + c0 + 0], run0);
                        atomicAdd(&pooled[(size_t)gp * HD + c0 + 1], run1);
                    }
                    run0 = xv.x; run1 = xv.y; gp = g;
                } else {
                    run0 += xv.x; run1 += xv.y;
                }
            }
            if (gp >= 0) {
                atomicAdd(&pooled[(size_t)gp * HD + c0 + 0], run0);
                atomicAdd(&pooled[(size_t)gp * HD + c0 + 1], run1);
            }
        }
    } else {
        // ---- epilogue: bf16 restage through LDS, coalesced row stores ----
#pragma unroll
        for (int s = 0; s < 2; s++)
#pragma unroll
            for (int nt = 0; nt < 8; nt++) {
                float bj = b3[nt * 16 + m];
#pragma unroll
                for (int r = 0; r < 4; r++)
                    sh[wave][s * 16 + quad * 4 + r][nt * 16 + m] =
                        bf16_hi(fmaxf(acc[s][nt][r] + bj, 0.f));
            }
#pragma unroll
        for (int io = 0; io < 8; io++) {
            int row32 = io * 4 + quad;
            int col = m * 8;
            int n2 = nodeBase + row32;
            bf16x8 v = *(const bf16x8*)&sh[wave][row32][col];
            if (n2 < NN) *(bf16x8*)&out[(size_t)n2 * HD + col] = v;
        }
    }
}

// ---------------------------------------------------------------------------
// Classifier head: one block (128 threads) per graph.
// ---------------------------------------------------------------------------
__launch_bounds__(128)
__global__ void head(const float* __restrict__ pooled, const int* __restrict__ cntg,
                     const float* __restrict__ fc0_w, const float* __restrict__ fc0_b,
                     const float* __restrict__ fc1_w, const float* __restrict__ fc1_b,
                     const float* __restrict__ out_w, const float* __restrict__ out_b,
                     float* __restrict__ out) {
    int g = blockIdx.x;
    int j = threadIdx.x;
    __shared__ float s0[HD];
    __shared__ float s1[HD];
    int c = cntg[g];
    float cf = (float)(c > 1 ? c : 1);
    s0[j] = pooled[(size_t)g * HD + j] / cf;
    __syncthreads();

    float acc = fc0_b[j];
    for (int k = 0; k < HD; k += 4) {
        float4 hv = *(const float4*)&s0[k];
        acc = fmaf(hv.x, fc0_w[(k + 0) * HD + j], acc);
        acc = fmaf(hv.y, fc0_w[(k + 1) * HD + j], acc);
        acc = fmaf(hv.z, fc0_w[(k + 2) * HD + j], acc);
        acc = fmaf(hv.w, fc0_w[(k + 3) * HD + j], acc);
    }
    s1[j] = fmaxf(acc, 0.0f);
    __syncthreads();

    acc = fc1_b[j];
    for (int k = 0; k < HD; k += 4) {
        float4 hv = *(const float4*)&s1[k];
        acc = fmaf(hv.x, fc1_w[(k + 0) * HD + j], acc);
        acc = fmaf(hv.y, fc1_w[(k + 1) * HD + j], acc);
        acc = fmaf(hv.z, fc1_w[(k + 2) * HD + j], acc);
        acc = fmaf(hv.w, fc1_w[(k + 3) * HD + j], acc);
    }
    float v = fmaxf(acc, 0.0f);

    float p0 = v * out_w[j * 2 + 0];
    float p1 = v * out_w[j * 2 + 1];
    __syncthreads();
    s0[j] = p0;
    s1[j] = p1;
    __syncthreads();
    for (int off = 64; off >= 1; off >>= 1) {
        if (j < off) {
            s0[j] += s0[j + off];
            s1[j] += s1[j + off];
        }
        __syncthreads();
    }
    if (j == 0) {
        out[(size_t)g * 2 + 0] = s0[0] + out_b[0];
        out[(size_t)g * 2 + 1] = s1[0] + out_b[1];
    }
}

// ---------------------------------------------------------------------------
extern "C" void kernel_launch(void* const* d_in, const int* in_sizes, int n_in,
                              void* d_out, int out_size, void* d_ws, size_t ws_size,
                              hipStream_t stream) {
    const float* x     = (const float*)d_in[0];
    const int*   ei    = (const int*)d_in[1];
    const int*   batch = (const int*)d_in[2];
    const float* cw[3][6];
    for (int i = 0; i < 3; i++)
        for (int k = 0; k < 6; k++) cw[i][k] = (const float*)d_in[3 + 6 * i + k];
    const float* fc0_w = (const float*)d_in[21];
    const float* fc0_b = (const float*)d_in[22];
    const float* fc1_w = (const float*)d_in[23];
    const float* fc1_b = (const float*)d_in[24];
    const float* out_w = (const float*)d_in[25];
    const float* out_b = (const float*)d_in[26];
    float* out = (float*)d_out;

    char* ws = (char*)d_ws;
    size_t off = 0;
    auto carve = [&](size_t bytes) {
        void* p = ws + off;
        off += (bytes + 255) & ~(size_t)255;
        return p;
    };
    int*   cnt_node = (int*)carve((size_t)NN * 4);
    int*   cntg     = (int*)carve((size_t)GG * 4);
    float* pooled   = (float*)carve((size_t)GG * HD * 4);
    int*   bucket   = (int*)carve((size_t)(NP + 16) * CAP * 4);  // padded past NN for coop staging reads
    unsigned short* hA = (unsigned short*)carve((size_t)NP * HD * 2);
    unsigned short* hB = (unsigned short*)carve((size_t)NP * HD * 2);
    unsigned short* wHi[9];
    unsigned short* wLo[9];
    int wK[9] = {F_IN, HD, HD, HD, HD, HD, HD, HD, HD};
    for (int i = 0; i < 9; i++) {
        wHi[i] = (unsigned short*)carve((size_t)wK[i] * HD * 2);
        wLo[i] = (unsigned short*)carve((size_t)wK[i] * HD * 2);
    }
    (void)ws_size;

    init_zero<<<(GG * HD + 255) / 256, 256, 0, stream>>>(cnt_node, cntg, pooled);
    build_graph<<<(EE + 255) / 256, 256, 0, stream>>>(ei, batch, cnt_node, cntg, bucket);

    PrepArgs pa;
    for (int l = 0; l < 3; l++)
        for (int s = 0; s < 3; s++) {
            int i = l * 3 + s;
            pa.d[i].src = cw[l][2 * s];
            pa.d[i].dhi = wHi[i];
            pa.d[i].dlo = wLo[i];
            pa.d[i].K = wK[i];
        }
    prep_weights<<<dim3(16, 9), 256, 0, stream>>>(pa);

    const int blocks = NP / 128;  // 1172

    // ---- GIN layer 0 (K=32, fp32 in): x -> hA (bf16) ----
    gin_layer<F_IN, false, false, false><<<blocks, 256, 0, stream>>>(x, cnt_node, bucket,
        wHi[0], wLo[0], cw[0][1], wHi[1], wLo[1], cw[0][3], wHi[2], wLo[2], cw[0][5],
        hA, batch, pooled);
    // ---- GIN layer 1 (bf16 in, COOP gather A/B arm): hA -> hB ----
    gin_layer<HD, true, true, false><<<blocks, 256, 0, stream>>>(hA, cnt_node, bucket,
        wHi[3], wLo[3], cw[1][1], wHi[4], wLo[4], cw[1][3], wHi[5], wLo[5], cw[1][5],
        hB, batch, pooled);
    // ---- GIN layer 2 (bf16 in, baseline gather, fused pool): hB -> pooled ----
    gin_layer<HD, true, false, true><<<blocks, 256, 0, stream>>>(hB, cnt_node, bucket,
        wHi[6], wLo[6], cw[2][1], wHi[7], wLo[7], cw[2][3], wHi[8], wLo[8], cw[2][5],
        nullptr, batch, pooled);

    // ---- head ----
    head<<<GG, 128, 0, stream>>>(pooled, cntg, fc0_w, fc0_b, fc1_w, fc1_b, out_w, out_b, out);
}